// Round 12
// baseline (281.405 us; speedup 1.0000x reference)
//
#include <hip/hip_runtime.h>
#include <hip/hip_cooperative_groups.h>
#include <hip/hip_bf16.h>
#include <cstdint>
#include <cstddef>

namespace cg = cooperative_groups;

#define NF 256   // features
#define NG 512   // hidden (2F)
#define NC 64    // classes
#define NB 8192  // batch
#define NK 16    // active rules
#define BT 64    // fs batch tile

typedef __attribute__((ext_vector_type(8))) short short8;
typedef __attribute__((ext_vector_type(4))) float floatx4;

__device__ __forceinline__ unsigned short f2bf(float f) {
    union { float f; unsigned int u; } a; a.f = f;
    unsigned int u = a.u;
    u += 0x7fffu + ((u >> 16) & 1u);   // RNE
    return (unsigned short)(u >> 16);
}
__device__ __forceinline__ float elu1(float z) {
    return z > 0.0f ? z : (__expf(z) - 1.0f);
}
// HW-packed f32x2 -> bf16x2 (v_cvt_pk_bf16_f32, RNE — bit-identical to f2bf)
__device__ __forceinline__ unsigned int pk2bf(float a, float b) {
    __hip_bfloat162 h = __float22bfloat162_rn(make_float2(a, b));
    union { __hip_bfloat162 h; unsigned int u; } cv; cv.h = h; return cv.u;
}

// LDS-only barrier: orders ds ops across the workgroup WITHOUT draining vmcnt.
__device__ __forceinline__ void bar_lds() {
    __builtin_amdgcn_sched_barrier(0);
    asm volatile("s_waitcnt lgkmcnt(0)" ::: "memory");
    __builtin_amdgcn_s_barrier();
    __builtin_amdgcn_sched_barrier(0);
}

// weight conversion mapping (shared by mega stage-0 and fallback conv_kernel)
__device__ __forceinline__ void conv_one(
    int i, const float* __restrict__ W1, const float* __restrict__ W2,
    const float* __restrict__ Wc, unsigned short* __restrict__ wb)
{
    if (i < 131072) {            // W1t: 32 N-blocks x 8 K-blocks
        int e = i & 7, l = (i >> 3) & 63, K = (i >> 9) & 7, N = i >> 12;
        int src = (N * 16 + (l & 15)) * NF + K * 32 + (l >> 4) * 8 + e;
        wb[i] = f2bf(W1[src]);
    } else if (i < 262144) {     // W2t: 16 N-blocks x 16 K-blocks
        int o = i - 131072;
        int e = o & 7, l = (o >> 3) & 63, K = (o >> 9) & 15, N = o >> 13;
        int src = (N * 16 + (l & 15)) * NG + K * 32 + (l >> 4) * 8 + e;
        wb[i] = f2bf(W2[src]);
    } else if (i < 786432) {     // Wct: 32 rules x 4 N-blocks x 8 K-blocks
        int o = i - 262144;
        int e = o & 7, l = (o >> 3) & 63, K = (o >> 9) & 7, N = (o >> 12) & 3, r = o >> 14;
        int src = (r * NC + N * 16 + (l & 15)) * NF + K * 32 + (l >> 4) * 8 + e;
        wb[i] = f2bf(Wc[src]);
    }
}

// ============================================================================
// MEGA KERNEL (cooperative): conv -> grid.sync -> fs x4 tiles -> grid.sync -> cons
// 512 blocks x 256 threads, 2 blocks/CU (exactly co-resident on 256 CUs).
// fs body is verbatim round-10/11 (95-97us verified); cons is the round-11
// body refit to 4 waves (wave = class group, all 16 rules serial, no pred[]).
// ============================================================================
__global__ __launch_bounds__(256, 2) void mega_kernel(
    const float* __restrict__ x, const float* __restrict__ proto,
    const float* __restrict__ var, const float* __restrict__ W1,
    const float* __restrict__ b1, const float* __restrict__ W2,
    const float* __restrict__ b2, const float* __restrict__ W3,
    const float* __restrict__ b3, const float* __restrict__ Wc,
    const float* __restrict__ bc, const int* __restrict__ ridx,
    unsigned short* __restrict__ W1b, unsigned short* __restrict__ W2b,
    unsigned short* __restrict__ Wcb, float* __restrict__ fsi,
    float* __restrict__ outp, float* __restrict__ fire_out)
{
    extern __shared__ unsigned short smem[];
    __shared__ float part[4][64];
    cg::grid_group grid = cg::this_grid();

    const int t   = threadIdx.x;
    const int pid = blockIdx.x;

    // ---- stage 0: weight fp32 -> bf16 (grid-stride, exactly 6 iterations) ----
#pragma unroll 1
    for (int i = pid * 256 + t; i < 786432; i += 512 * 256)
        conv_one(i, W1, W2, Wc, W1b);   // W1b is wb base
    grid.sync();

    // ---- stage 1: fs over 4 tiles --------------------------------------------
    unsigned short* mv   = smem;              // [64][256] swizzled (512 B rows)
    unsigned short* cbuf = smem + 64 * 256;   // [64][256] swizzled

    // XCD-chunked swizzle (bijective, 512%8==0)
    const int lg    = (pid & 7) * 64 + (pid >> 3);
    const int kidx  = lg & 15;
    const int stile = lg >> 4;                // 0..31
    const int r     = ridx[kidx];

    const int wave = t >> 6, lane = t & 63;
    const int ln = lane & 15, lq = lane >> 4;
    const int sxr = (ln & 7) << 4;            // swizzle term (row&7 == ln&7)

    // rule constants (hoisted across tiles)
    const int col   = (t & 63) * 4;
    const int colb  = (t & 63) * 8;
    const int rbase = t >> 6;                 // 0..3
    const float4 p4 = *(const float4*)(proto + (size_t)r * NF + col);
    float ix, iy, iz, iw;
    {
        float4 v4 = *(const float4*)(var + (size_t)r * NF + col);
        float cx = fminf(fmaxf(v4.x, 1e-4f), 0.1f);
        float cy = fminf(fmaxf(v4.y, 1e-4f), 0.1f);
        float cz = fminf(fmaxf(v4.z, 1e-4f), 0.1f);
        float cw = fminf(fmaxf(v4.w, 1e-4f), 0.1f);
        const float L2E = 1.44269504088896340736f;   // fold log2e: __expf(z)
        ix = (0.5f * L2E) / (cx * cx);               // == exp2(z*log2e)
        iy = (0.5f * L2E) / (cy * cy);
        iz = (0.5f * L2E) / (cz * cz);
        iw = (0.5f * L2E) / (cw * cw);
    }

#pragma unroll 1
    for (int it = 0; it < 4; ++it) {
        const int b0 = stile * 256 + it * BT;

        // ---- P0: membership ----
#pragma unroll 4
        for (int i = 0; i < 16; ++i) {
            int row = i * 4 + rbase;
            const float4 xv = *(const float4*)(x + (size_t)(b0 + row) * NF + col);
            float dx = xv.x - p4.x, dy = xv.y - p4.y, dz = xv.z - p4.z, dw = xv.w - p4.w;
            uint2 pk;
            pk.x = pk2bf(exp2f(-dx * dx * ix), exp2f(-dy * dy * iy));
            pk.y = pk2bf(exp2f(-dz * dz * iz), exp2f(-dw * dw * iw));
            *(uint2*)((char*)mv + row * 512 + (colb ^ ((row & 7) << 4))) = pk;
        }
        bar_lds();

        floatx4 acc2[4][4];
#pragma unroll
        for (int mi = 0; mi < 4; ++mi)
#pragma unroll
            for (int ni = 0; ni < 4; ++ni) {
                floatx4 z = {0.0f, 0.0f, 0.0f, 0.0f};
                acc2[mi][ni] = z;
            }

#pragma unroll 1
        for (int c = 0; c < 2; ++c) {
            // ---- P1 chunk c ----
            floatx4 acc1[4][4];
#pragma unroll
            for (int mi = 0; mi < 4; ++mi)
#pragma unroll
                for (int ni = 0; ni < 4; ++ni) {
                    floatx4 z = {0.0f, 0.0f, 0.0f, 0.0f};
                    acc1[mi][ni] = z;
                }
            const unsigned short* w1p = W1b + c * 65536 + wave * 16384 + lane * 8;
#pragma unroll 2
            for (int k0i = 0; k0i < 8; ++k0i) {
                short8 a[4], b[4];
#pragma unroll
                for (int mi = 0; mi < 4; ++mi)
                    a[mi] = *(const short8*)(w1p + mi * 4096 + k0i * 512);
#pragma unroll
                for (int ni = 0; ni < 4; ++ni)
                    b[ni] = *(const short8*)((const char*)mv + (ni * 16 + ln) * 512
                                             + ((k0i * 64 + lq * 16) ^ sxr));
#pragma unroll
                for (int ni = 0; ni < 4; ++ni)
#pragma unroll
                    for (int mi = 0; mi < 4; ++mi)
                        acc1[mi][ni] = __builtin_amdgcn_mfma_f32_16x16x32_bf16(
                            a[mi], b[ni], acc1[mi][ni], 0, 0, 0);
            }
            bar_lds();
            // ---- ELU + bias -> cbuf ----
#pragma unroll
            for (int mi = 0; mi < 4; ++mi) {
                const int nl = wave * 64 + mi * 16 + lq * 4;
                const float4 b4 = *(const float4*)(b1 + c * 256 + nl);
#pragma unroll
                for (int ni = 0; ni < 4; ++ni) {
                    uint2 pk;
                    pk.x = pk2bf(elu1(acc1[mi][ni][0] + b4.x),
                                 elu1(acc1[mi][ni][1] + b4.y));
                    pk.y = pk2bf(elu1(acc1[mi][ni][2] + b4.z),
                                 elu1(acc1[mi][ni][3] + b4.w));
                    *(uint2*)((char*)cbuf + (ni * 16 + ln) * 512 + ((nl * 2) ^ sxr)) = pk;
                }
            }
            bar_lds();
            // ---- P2 chunk c ----
            const unsigned short* w2p = W2b + wave * 32768 + c * 8 * 512 + lane * 8;
#pragma unroll 2
            for (int k0i = 0; k0i < 8; ++k0i) {
                short8 a[4], b[4];
#pragma unroll
                for (int mi = 0; mi < 4; ++mi)
                    a[mi] = *(const short8*)(w2p + mi * 8192 + k0i * 512);
#pragma unroll
                for (int ni = 0; ni < 4; ++ni)
                    b[ni] = *(const short8*)((const char*)cbuf + (ni * 16 + ln) * 512
                                             + ((k0i * 64 + lq * 16) ^ sxr));
#pragma unroll
                for (int ni = 0; ni < 4; ++ni)
#pragma unroll
                    for (int mi = 0; mi < 4; ++mi)
                        acc2[mi][ni] = __builtin_amdgcn_mfma_f32_16x16x32_bf16(
                            a[mi], b[ni], acc2[mi][ni], 0, 0, 0);
            }
        }

        // ---- P3 -> fsi ----
        float w3v[4][4], b2v[4][4];
#pragma unroll
        for (int mi = 0; mi < 4; ++mi) {
            const int np = wave * 64 + mi * 16 + lq * 4;
            const float4 wv = *(const float4*)(W3 + np);
            const float4 bv = *(const float4*)(b2 + np);
            w3v[mi][0] = wv.x; w3v[mi][1] = wv.y; w3v[mi][2] = wv.z; w3v[mi][3] = wv.w;
            b2v[mi][0] = bv.x; b2v[mi][1] = bv.y; b2v[mi][2] = bv.z; b2v[mi][3] = bv.w;
        }
#pragma unroll
        for (int ni = 0; ni < 4; ++ni) {
            float s = 0.0f;
#pragma unroll
            for (int mi = 0; mi < 4; ++mi)
#pragma unroll
                for (int rg = 0; rg < 4; ++rg)
                    s += elu1(acc2[mi][ni][rg] + b2v[mi][rg]) * w3v[mi][rg];
            s += __shfl_xor(s, 16);
            s += __shfl_xor(s, 32);
            if (lq == 0) part[wave][ni * 16 + ln] = s;
        }
        bar_lds();
        if (t < 64) {
            float s = b3[0];
#pragma unroll
            for (int w = 0; w < 4; ++w) s += part[w][t];
            fsi[(size_t)kidx * NB + b0 + t] = s;
        }
    }
    grid.sync();

    // ---- stage 2: cons (block = 16 rows; wave = class group, all 16 rules) ----
    {
        unsigned short* xl  = smem;                    // [16][264]
        float*          fire = (float*)(smem + 16 * 264);  // [16][16]
        const int b0c = pid * 16;

        int rr[NK];
#pragma unroll
        for (int k = 0; k < NK; ++k) rr[k] = ridx[k];

        // x -> bf16 LDS (16 rows x 256 cols, 256 threads x 4 float4)
#pragma unroll
        for (int i = 0; i < 4; ++i) {
            int idx = t + i * 256;
            int row = idx >> 6, cc = (idx & 63) * 4;
            const float4 xv = *(const float4*)(x + (size_t)(b0c + row) * NF + cc);
            uint2 pk;
            pk.x = pk2bf(xv.x, xv.y);
            pk.y = pk2bf(xv.z, xv.w);
            *(uint2*)(xl + row * 264 + cc) = pk;
        }
        // softmax over 16 rules: thread = (row = t>>4, k = t&15)
        {
            const int row = t >> 4, k = t & 15;
            float v = fsi[(size_t)k * NB + b0c + row];
            float mx = v;
            mx = fmaxf(mx, __shfl_xor(mx, 1));
            mx = fmaxf(mx, __shfl_xor(mx, 2));
            mx = fmaxf(mx, __shfl_xor(mx, 4));
            mx = fmaxf(mx, __shfl_xor(mx, 8));
            float e = __expf(v - mx);
            float sum = e;
            sum += __shfl_xor(sum, 1);
            sum += __shfl_xor(sum, 2);
            sum += __shfl_xor(sum, 4);
            sum += __shfl_xor(sum, 8);
            float fv = e / sum;
            fire[row * 16 + k] = fv;
            fire_out[(size_t)b0c * NK + t] = fv;
        }
        __syncthreads();

        const int nb = wave * 16;     // class group = wave (4 waves x 16 classes)

        short8 afr[8];
#pragma unroll
        for (int k0i = 0; k0i < 8; ++k0i)
            afr[k0i] = *(const short8*)(xl + ln * 264 + k0i * 32 + lq * 8);

        floatx4 oacc = {0.0f, 0.0f, 0.0f, 0.0f};
#pragma unroll
        for (int kp = 0; kp < 8; ++kp) {
            const int k0r = kp * 2;
            const int r0 = rr[k0r], r1 = rr[k0r + 1];
            const unsigned short* Wr0 = Wcb + ((size_t)(r0 * 4 + wave) * 8) * 512 + lane * 8;
            const unsigned short* Wr1 = Wcb + ((size_t)(r1 * 4 + wave) * 8) * 512 + lane * 8;
            floatx4 a0 = {0.0f, 0.0f, 0.0f, 0.0f};
            floatx4 a1 = {0.0f, 0.0f, 0.0f, 0.0f};
#pragma unroll
            for (int k0i = 0; k0i < 8; ++k0i) {
                short8 bb0 = *(const short8*)(Wr0 + k0i * 512);
                short8 bb1 = *(const short8*)(Wr1 + k0i * 512);
                a0 = __builtin_amdgcn_mfma_f32_16x16x32_bf16(afr[k0i], bb0, a0, 0, 0, 0);
                a1 = __builtin_amdgcn_mfma_f32_16x16x32_bf16(afr[k0i], bb1, a1, 0, 0, 0);
            }
            const float bias0 = bc[(size_t)r0 * NC + nb + ln];
            const float bias1 = bc[(size_t)r1 * NC + nb + ln];
#pragma unroll
            for (int rg = 0; rg < 4; ++rg) {
                const int row = lq * 4 + rg;
                oacc[rg] += fmaxf(a0[rg] + bias0, 0.0f) * fire[row * 16 + k0r]
                          + fmaxf(a1[rg] + bias1, 0.0f) * fire[row * 16 + k0r + 1];
            }
        }
#pragma unroll
        for (int rg = 0; rg < 4; ++rg)
            outp[(size_t)(b0c + lq * 4 + rg) * NC + nb + ln] = oacc[rg];
    }
}

// ============================================================================
// FALLBACK PATH (round-11 kernels, verbatim) — used if cooperative launch fails
// ============================================================================
__global__ __launch_bounds__(256) void conv_kernel(
    const float* __restrict__ W1, const float* __restrict__ W2,
    const float* __restrict__ Wc, unsigned short* __restrict__ wb)
{
    int i = blockIdx.x * 256 + threadIdx.x;
    conv_one(i, W1, W2, Wc, wb);
}

__global__ __launch_bounds__(256, 2) void fs_kernel(
    const float* __restrict__ x, const float* __restrict__ proto,
    const float* __restrict__ var, const unsigned short* __restrict__ W1b,
    const float* __restrict__ b1, const unsigned short* __restrict__ W2b,
    const float* __restrict__ b2, const float* __restrict__ W3,
    const float* __restrict__ b3, const int* __restrict__ ridx,
    float* __restrict__ fsi)
{
    extern __shared__ unsigned short smem[];
    __shared__ float part[4][64];
    unsigned short* mv   = smem;
    unsigned short* cbuf = smem + 64 * 256;

    const int t   = threadIdx.x;
    const int pid = blockIdx.x;
    const int lg  = (pid & 7) * 256 + (pid >> 3);
    const int kidx = lg & 15;
    const int tile = lg >> 4;
    const int r    = ridx[kidx];
    const int b0   = tile * BT;

    const int wave = t >> 6, lane = t & 63;
    const int ln = lane & 15, lq = lane >> 4;
    const int sxr = (ln & 7) << 4;

    {
        const int col   = (t & 63) * 4;
        const int colb  = (t & 63) * 8;
        const int rbase = t >> 6;
        const float4 p4 = *(const float4*)(proto + (size_t)r * NF + col);
        float4 v4 = *(const float4*)(var + (size_t)r * NF + col);
        float cx = fminf(fmaxf(v4.x, 1e-4f), 0.1f);
        float cy = fminf(fmaxf(v4.y, 1e-4f), 0.1f);
        float cz = fminf(fmaxf(v4.z, 1e-4f), 0.1f);
        float cw = fminf(fmaxf(v4.w, 1e-4f), 0.1f);
        const float L2E = 1.44269504088896340736f;
        float ix = (0.5f * L2E) / (cx * cx);
        float iy = (0.5f * L2E) / (cy * cy);
        float iz = (0.5f * L2E) / (cz * cz);
        float iw = (0.5f * L2E) / (cw * cw);
#pragma unroll 4
        for (int i = 0; i < 16; ++i) {
            int row = i * 4 + rbase;
            const float4 xv = *(const float4*)(x + (size_t)(b0 + row) * NF + col);
            float dx = xv.x - p4.x, dy = xv.y - p4.y, dz = xv.z - p4.z, dw = xv.w - p4.w;
            uint2 pk;
            pk.x = pk2bf(exp2f(-dx * dx * ix), exp2f(-dy * dy * iy));
            pk.y = pk2bf(exp2f(-dz * dz * iz), exp2f(-dw * dw * iw));
            *(uint2*)((char*)mv + row * 512 + (colb ^ ((row & 7) << 4))) = pk;
        }
    }
    bar_lds();

    floatx4 acc2[4][4];
#pragma unroll
    for (int mi = 0; mi < 4; ++mi)
#pragma unroll
        for (int ni = 0; ni < 4; ++ni) {
            floatx4 z = {0.0f, 0.0f, 0.0f, 0.0f};
            acc2[mi][ni] = z;
        }

#pragma unroll 1
    for (int c = 0; c < 2; ++c) {
        floatx4 acc1[4][4];
#pragma unroll
        for (int mi = 0; mi < 4; ++mi)
#pragma unroll
            for (int ni = 0; ni < 4; ++ni) {
                floatx4 z = {0.0f, 0.0f, 0.0f, 0.0f};
                acc1[mi][ni] = z;
            }
        const unsigned short* w1p = W1b + c * 65536 + wave * 16384 + lane * 8;
#pragma unroll 2
        for (int k0i = 0; k0i < 8; ++k0i) {
            short8 a[4], b[4];
#pragma unroll
            for (int mi = 0; mi < 4; ++mi)
                a[mi] = *(const short8*)(w1p + mi * 4096 + k0i * 512);
#pragma unroll
            for (int ni = 0; ni < 4; ++ni)
                b[ni] = *(const short8*)((const char*)mv + (ni * 16 + ln) * 512
                                         + ((k0i * 64 + lq * 16) ^ sxr));
#pragma unroll
            for (int ni = 0; ni < 4; ++ni)
#pragma unroll
                for (int mi = 0; mi < 4; ++mi)
                    acc1[mi][ni] = __builtin_amdgcn_mfma_f32_16x16x32_bf16(
                        a[mi], b[ni], acc1[mi][ni], 0, 0, 0);
        }
        bar_lds();
#pragma unroll
        for (int mi = 0; mi < 4; ++mi) {
            const int nl = wave * 64 + mi * 16 + lq * 4;
            const float4 b4 = *(const float4*)(b1 + c * 256 + nl);
#pragma unroll
            for (int ni = 0; ni < 4; ++ni) {
                uint2 pk;
                pk.x = pk2bf(elu1(acc1[mi][ni][0] + b4.x),
                             elu1(acc1[mi][ni][1] + b4.y));
                pk.y = pk2bf(elu1(acc1[mi][ni][2] + b4.z),
                             elu1(acc1[mi][ni][3] + b4.w));
                *(uint2*)((char*)cbuf + (ni * 16 + ln) * 512 + ((nl * 2) ^ sxr)) = pk;
            }
        }
        bar_lds();
        const unsigned short* w2p = W2b + wave * 32768 + c * 8 * 512 + lane * 8;
#pragma unroll 2
        for (int k0i = 0; k0i < 8; ++k0i) {
            short8 a[4], b[4];
#pragma unroll
            for (int mi = 0; mi < 4; ++mi)
                a[mi] = *(const short8*)(w2p + mi * 8192 + k0i * 512);
#pragma unroll
            for (int ni = 0; ni < 4; ++ni)
                b[ni] = *(const short8*)((const char*)cbuf + (ni * 16 + ln) * 512
                                         + ((k0i * 64 + lq * 16) ^ sxr));
#pragma unroll
            for (int ni = 0; ni < 4; ++ni)
#pragma unroll
                for (int mi = 0; mi < 4; ++mi)
                    acc2[mi][ni] = __builtin_amdgcn_mfma_f32_16x16x32_bf16(
                        a[mi], b[ni], acc2[mi][ni], 0, 0, 0);
        }
    }

    float w3v[4][4], b2v[4][4];
#pragma unroll
    for (int mi = 0; mi < 4; ++mi) {
        const int np = wave * 64 + mi * 16 + lq * 4;
        const float4 wv = *(const float4*)(W3 + np);
        const float4 bv = *(const float4*)(b2 + np);
        w3v[mi][0] = wv.x; w3v[mi][1] = wv.y; w3v[mi][2] = wv.z; w3v[mi][3] = wv.w;
        b2v[mi][0] = bv.x; b2v[mi][1] = bv.y; b2v[mi][2] = bv.z; b2v[mi][3] = bv.w;
    }
#pragma unroll
    for (int ni = 0; ni < 4; ++ni) {
        float s = 0.0f;
#pragma unroll
        for (int mi = 0; mi < 4; ++mi)
#pragma unroll
            for (int rg = 0; rg < 4; ++rg)
                s += elu1(acc2[mi][ni][rg] + b2v[mi][rg]) * w3v[mi][rg];
        s += __shfl_xor(s, 16);
        s += __shfl_xor(s, 32);
        if (lq == 0) part[wave][ni * 16 + ln] = s;
    }
    bar_lds();
    if (t < 64) {
        float s = b3[0];
#pragma unroll
        for (int w = 0; w < 4; ++w) s += part[w][t];
        fsi[(size_t)kidx * NB + b0 + t] = s;
    }
}

__global__ __launch_bounds__(512, 4) void cons_kernel(
    const float* __restrict__ x, const unsigned short* __restrict__ Wcb,
    const float* __restrict__ bc, const float* __restrict__ fsi,
    const int* __restrict__ ridx, float* __restrict__ outp,
    float* __restrict__ fire_out)
{
    __shared__ unsigned short xl[16 * 264];
    __shared__ float fire[16][NK];
    __shared__ float pred[4][16][16];

    const int t  = threadIdx.x;
    const int b0 = blockIdx.x * 16;

    int rr[NK];
#pragma unroll
    for (int k = 0; k < NK; ++k) rr[k] = ridx[k];

    {
        int idx = t;
#pragma unroll
        for (int i = 0; i < 2; ++i, idx += 512) {
            int row = idx >> 6, col = (idx & 63) * 4;
            const float4 xv = *(const float4*)(x + (size_t)(b0 + row) * NF + col);
            uint2 pk;
            pk.x = pk2bf(xv.x, xv.y);
            pk.y = pk2bf(xv.z, xv.w);
            *(uint2*)(xl + row * 264 + col) = pk;
        }
    }
    if (t < 256) {
        const int row = t >> 4, k = t & 15;
        float v = fsi[(size_t)k * NB + b0 + row];
        float mx = v;
        mx = fmaxf(mx, __shfl_xor(mx, 1));
        mx = fmaxf(mx, __shfl_xor(mx, 2));
        mx = fmaxf(mx, __shfl_xor(mx, 4));
        mx = fmaxf(mx, __shfl_xor(mx, 8));
        float e = __expf(v - mx);
        float sum = e;
        sum += __shfl_xor(sum, 1);
        sum += __shfl_xor(sum, 2);
        sum += __shfl_xor(sum, 4);
        sum += __shfl_xor(sum, 8);
        float fv = e / sum;
        fire[row][k] = fv;
        fire_out[(size_t)b0 * NK + t] = fv;
    }
    __syncthreads();

    const int wave = t >> 6, lane = t & 63;
    const int ln = lane & 15, lq = lane >> 4;
    const int cg2 = wave & 3, half = wave >> 2;
    const int nb = cg2 * 16;

    short8 afr[8];
#pragma unroll
    for (int k0i = 0; k0i < 8; ++k0i)
        afr[k0i] = *(const short8*)(xl + ln * 264 + k0i * 32 + lq * 8);

    floatx4 oacc = {0.0f, 0.0f, 0.0f, 0.0f};
#pragma unroll
    for (int kp = 0; kp < 4; ++kp) {
        const int k0r = half * 8 + kp * 2;
        const int r0 = rr[k0r], r1 = rr[k0r + 1];
        const unsigned short* Wr0 = Wcb + ((size_t)(r0 * 4 + cg2) * 8) * 512 + lane * 8;
        const unsigned short* Wr1 = Wcb + ((size_t)(r1 * 4 + cg2) * 8) * 512 + lane * 8;
        floatx4 a0 = {0.0f, 0.0f, 0.0f, 0.0f};
        floatx4 a1 = {0.0f, 0.0f, 0.0f, 0.0f};
#pragma unroll
        for (int k0i = 0; k0i < 8; ++k0i) {
            short8 bb0 = *(const short8*)(Wr0 + k0i * 512);
            short8 bb1 = *(const short8*)(Wr1 + k0i * 512);
            a0 = __builtin_amdgcn_mfma_f32_16x16x32_bf16(afr[k0i], bb0, a0, 0, 0, 0);
            a1 = __builtin_amdgcn_mfma_f32_16x16x32_bf16(afr[k0i], bb1, a1, 0, 0, 0);
        }
        const float bias0 = bc[(size_t)r0 * NC + nb + ln];
        const float bias1 = bc[(size_t)r1 * NC + nb + ln];
#pragma unroll
        for (int rg = 0; rg < 4; ++rg) {
            const int row = lq * 4 + rg;
            oacc[rg] += fmaxf(a0[rg] + bias0, 0.0f) * fire[row][k0r]
                      + fmaxf(a1[rg] + bias1, 0.0f) * fire[row][k0r + 1];
        }
    }
    if (half == 1) {
#pragma unroll
        for (int rg = 0; rg < 4; ++rg)
            pred[cg2][lq * 4 + rg][ln] = oacc[rg];
    }
    __syncthreads();
    if (half == 0) {
#pragma unroll
        for (int rg = 0; rg < 4; ++rg)
            outp[(size_t)(b0 + lq * 4 + rg) * NC + nb + ln] =
                oacc[rg] + pred[cg2][lq * 4 + rg][ln];
    }
}

extern "C" void kernel_launch(void* const* d_in, const int* in_sizes, int n_in,
                              void* d_out, int out_size, void* d_ws, size_t ws_size,
                              hipStream_t stream)
{
    (void)in_sizes; (void)n_in; (void)out_size;
    if (ws_size < 2097152) return;

    const float* x     = (const float*)d_in[0];
    const float* proto = (const float*)d_in[1];
    const float* var   = (const float*)d_in[2];
    const float* W1    = (const float*)d_in[3];
    const float* b1    = (const float*)d_in[4];
    const float* W2    = (const float*)d_in[5];
    const float* b2    = (const float*)d_in[6];
    const float* W3    = (const float*)d_in[7];
    const float* b3    = (const float*)d_in[8];
    const float* Wc    = (const float*)d_in[9];
    const float* bc    = (const float*)d_in[10];
    const int*   ridx  = (const int*)d_in[11];

    unsigned short* wb  = (unsigned short*)d_ws;
    unsigned short* W1b = wb;                 // 131072 (fragment-transposed)
    unsigned short* W2b = wb + 131072;        // 131072 (fragment-transposed)
    unsigned short* Wcb = wb + 262144;        // 524288 (fragment-transposed)
    float* fsi = (float*)((char*)d_ws + (size_t)786432 * 2);

    float* outp     = (float*)d_out;
    float* fire_out = outp + (size_t)NB * NC;

    const int lds = 2 * 64 * 256 * 2;  // 65536 B dynamic
    hipFuncSetAttribute((const void*)mega_kernel,
                        hipFuncAttributeMaxDynamicSharedMemorySize, lds);
    hipFuncSetAttribute((const void*)fs_kernel,
                        hipFuncAttributeMaxDynamicSharedMemorySize, lds);

    void* args[] = { (void*)&x, (void*)&proto, (void*)&var, (void*)&W1,
                     (void*)&b1, (void*)&W2, (void*)&b2, (void*)&W3,
                     (void*)&b3, (void*)&Wc, (void*)&bc, (void*)&ridx,
                     (void*)&W1b, (void*)&W2b, (void*)&Wcb, (void*)&fsi,
                     (void*)&outp, (void*)&fire_out };
    hipError_t err = hipLaunchCooperativeKernel((const void*)mega_kernel,
                                                dim3(512), dim3(256),
                                                args, lds, stream);
    if (err != hipSuccess) {
        // fallback: verified round-11 3-kernel path
        conv_kernel<<<3072, 256, 0, stream>>>(W1, W2, Wc, wb);
        fs_kernel<<<2048, 256, lds, stream>>>(x, proto, var, W1b, b1, W2b, b2,
                                              W3, b3, ridx, fsi);
        cons_kernel<<<512, 512, 0, stream>>>(x, Wcb, bc, fsi, ridx, outp, fire_out);
    }
}

// Round 13
// 181.913 us; speedup vs baseline: 1.5469x; 1.5469x over previous
//
#include <hip/hip_runtime.h>
#include <hip/hip_bf16.h>
#include <cstdint>
#include <cstddef>

#define NF 256   // features
#define NG 512   // hidden (2F)
#define NC 64    // classes
#define NB 8192  // batch
#define NK 16    // active rules
#define BT 64    // fs batch tile

typedef __attribute__((ext_vector_type(8))) short short8;
typedef __attribute__((ext_vector_type(4))) float floatx4;

__device__ __forceinline__ unsigned short f2bf(float f) {
    union { float f; unsigned int u; } a; a.f = f;
    unsigned int u = a.u;
    u += 0x7fffu + ((u >> 16) & 1u);   // RNE
    return (unsigned short)(u >> 16);
}
__device__ __forceinline__ float elu1(float z) {
    return z > 0.0f ? z : (__expf(z) - 1.0f);
}
// HW-packed f32x2 -> bf16x2 (v_cvt_pk_bf16_f32, RNE — bit-identical to f2bf)
__device__ __forceinline__ unsigned int pk2bf(float a, float b) {
    __hip_bfloat162 h = __float22bfloat162_rn(make_float2(a, b));
    union { __hip_bfloat162 h; unsigned int u; } cv; cv.h = h; return cv.u;
}

// LDS-only barrier: orders ds ops across the workgroup WITHOUT draining vmcnt.
__device__ __forceinline__ void bar_lds() {
    __builtin_amdgcn_sched_barrier(0);
    asm volatile("s_waitcnt lgkmcnt(0)" ::: "memory");
    __builtin_amdgcn_s_barrier();
    __builtin_amdgcn_sched_barrier(0);
}

// ---------------- kernel 0: weights fp32 -> bf16, ALL FRAGMENT-TRANSPOSED ----
// (verbatim round 11 — verified)
__global__ __launch_bounds__(256) void conv_kernel(
    const float* __restrict__ W1, const float* __restrict__ W2,
    const float* __restrict__ Wc, unsigned short* __restrict__ wb)
{
    int i = blockIdx.x * 256 + threadIdx.x;
    if (i < 131072) {            // W1t: 32 N-blocks x 8 K-blocks
        int e = i & 7, l = (i >> 3) & 63, K = (i >> 9) & 7, N = i >> 12;
        int src = (N * 16 + (l & 15)) * NF + K * 32 + (l >> 4) * 8 + e;
        wb[i] = f2bf(W1[src]);
    } else if (i < 262144) {     // W2t: 16 N-blocks x 16 K-blocks
        int o = i - 131072;
        int e = o & 7, l = (o >> 3) & 63, K = (o >> 9) & 15, N = o >> 13;
        int src = (N * 16 + (l & 15)) * NG + K * 32 + (l >> 4) * 8 + e;
        wb[i] = f2bf(W2[src]);
    } else if (i < 786432) {     // Wct: 32 rules x 4 N-blocks x 8 K-blocks
        int o = i - 262144;
        int e = o & 7, l = (o >> 3) & 63, K = (o >> 9) & 7, N = (o >> 12) & 3, r = o >> 14;
        int src = (r * NC + N * 16 + (l & 15)) * NF + K * 32 + (l >> 4) * 8 + e;
        wb[i] = f2bf(Wc[src]);
    }
}

// ---------------- kernel 1: fused membership -> MLP -> fsi -------------------
// (verbatim round 10/11 — verified 95-97us)
__global__ __launch_bounds__(256, 2) void fs_kernel(
    const float* __restrict__ x, const float* __restrict__ proto,
    const float* __restrict__ var, const unsigned short* __restrict__ W1b,
    const float* __restrict__ b1, const unsigned short* __restrict__ W2b,
    const float* __restrict__ b2, const float* __restrict__ W3,
    const float* __restrict__ b3, const int* __restrict__ ridx,
    float* __restrict__ fsi)
{
    extern __shared__ unsigned short smem[];
    __shared__ float part[4][64];
    unsigned short* mv   = smem;              // [64][256] swizzled (512 B rows)
    unsigned short* cbuf = smem + 64 * 256;   // [64][256] swizzled, reused per chunk

    const int t   = threadIdx.x;
    const int pid = blockIdx.x;
    const int lg  = (pid & 7) * 256 + (pid >> 3);
    const int kidx = lg & 15;
    const int tile = lg >> 4;
    const int r    = ridx[kidx];
    const int b0   = tile * BT;

    const int wave = t >> 6, lane = t & 63;
    const int ln = lane & 15, lq = lane >> 4;
    const int sxr = (ln & 7) << 4;            // swizzle term (row&7 == ln&7)

    // ---- P0: membership mv = exp(-(x-p)^2/(2 v^2)), v=clip(var,1e-4,0.1) ----
    {
        const int col   = (t & 63) * 4;
        const int colb  = (t & 63) * 8;
        const int rbase = t >> 6;             // 0..3
        const float4 p4 = *(const float4*)(proto + (size_t)r * NF + col);
        float4 v4 = *(const float4*)(var + (size_t)r * NF + col);
        float cx = fminf(fmaxf(v4.x, 1e-4f), 0.1f);
        float cy = fminf(fmaxf(v4.y, 1e-4f), 0.1f);
        float cz = fminf(fmaxf(v4.z, 1e-4f), 0.1f);
        float cw = fminf(fmaxf(v4.w, 1e-4f), 0.1f);
        const float L2E = 1.44269504088896340736f;   // fold log2e: __expf(z)
        float ix = (0.5f * L2E) / (cx * cx);         // == exp2(z*log2e)
        float iy = (0.5f * L2E) / (cy * cy);
        float iz = (0.5f * L2E) / (cz * cz);
        float iw = (0.5f * L2E) / (cw * cw);
#pragma unroll 4
        for (int i = 0; i < 16; ++i) {
            int row = i * 4 + rbase;
            const float4 xv = *(const float4*)(x + (size_t)(b0 + row) * NF + col);
            float dx = xv.x - p4.x, dy = xv.y - p4.y, dz = xv.z - p4.z, dw = xv.w - p4.w;
            uint2 pk;
            pk.x = pk2bf(exp2f(-dx * dx * ix), exp2f(-dy * dy * iy));
            pk.y = pk2bf(exp2f(-dz * dz * iz), exp2f(-dw * dw * iw));
            *(uint2*)((char*)mv + row * 512 + (colb ^ ((row & 7) << 4))) = pk;
        }
    }
    bar_lds();

    floatx4 acc2[4][4];
#pragma unroll
    for (int mi = 0; mi < 4; ++mi)
#pragma unroll
        for (int ni = 0; ni < 4; ++ni) {
            floatx4 z = {0.0f, 0.0f, 0.0f, 0.0f};
            acc2[mi][ni] = z;
        }

#pragma unroll 1
    for (int c = 0; c < 2; ++c) {
        floatx4 acc1[4][4];
#pragma unroll
        for (int mi = 0; mi < 4; ++mi)
#pragma unroll
            for (int ni = 0; ni < 4; ++ni) {
                floatx4 z = {0.0f, 0.0f, 0.0f, 0.0f};
                acc1[mi][ni] = z;
            }
        const unsigned short* w1p = W1b + c * 65536 + wave * 16384 + lane * 8;
#pragma unroll 2
        for (int k0i = 0; k0i < 8; ++k0i) {
            short8 a[4], b[4];
#pragma unroll
            for (int mi = 0; mi < 4; ++mi)
                a[mi] = *(const short8*)(w1p + mi * 4096 + k0i * 512);
#pragma unroll
            for (int ni = 0; ni < 4; ++ni)
                b[ni] = *(const short8*)((const char*)mv + (ni * 16 + ln) * 512
                                         + ((k0i * 64 + lq * 16) ^ sxr));
#pragma unroll
            for (int ni = 0; ni < 4; ++ni)
#pragma unroll
                for (int mi = 0; mi < 4; ++mi)
                    acc1[mi][ni] = __builtin_amdgcn_mfma_f32_16x16x32_bf16(
                        a[mi], b[ni], acc1[mi][ni], 0, 0, 0);
        }
        bar_lds();
#pragma unroll
        for (int mi = 0; mi < 4; ++mi) {
            const int nl = wave * 64 + mi * 16 + lq * 4;
            const float4 b4 = *(const float4*)(b1 + c * 256 + nl);
#pragma unroll
            for (int ni = 0; ni < 4; ++ni) {
                uint2 pk;
                pk.x = pk2bf(elu1(acc1[mi][ni][0] + b4.x),
                             elu1(acc1[mi][ni][1] + b4.y));
                pk.y = pk2bf(elu1(acc1[mi][ni][2] + b4.z),
                             elu1(acc1[mi][ni][3] + b4.w));
                *(uint2*)((char*)cbuf + (ni * 16 + ln) * 512 + ((nl * 2) ^ sxr)) = pk;
            }
        }
        bar_lds();
        const unsigned short* w2p = W2b + wave * 32768 + c * 8 * 512 + lane * 8;
#pragma unroll 2
        for (int k0i = 0; k0i < 8; ++k0i) {
            short8 a[4], b[4];
#pragma unroll
            for (int mi = 0; mi < 4; ++mi)
                a[mi] = *(const short8*)(w2p + mi * 8192 + k0i * 512);
#pragma unroll
            for (int ni = 0; ni < 4; ++ni)
                b[ni] = *(const short8*)((const char*)cbuf + (ni * 16 + ln) * 512
                                         + ((k0i * 64 + lq * 16) ^ sxr));
#pragma unroll
            for (int ni = 0; ni < 4; ++ni)
#pragma unroll
                for (int mi = 0; mi < 4; ++mi)
                    acc2[mi][ni] = __builtin_amdgcn_mfma_f32_16x16x32_bf16(
                        a[mi], b[ni], acc2[mi][ni], 0, 0, 0);
        }
    }

    float w3v[4][4], b2v[4][4];
#pragma unroll
    for (int mi = 0; mi < 4; ++mi) {
        const int np = wave * 64 + mi * 16 + lq * 4;
        const float4 wv = *(const float4*)(W3 + np);
        const float4 bv = *(const float4*)(b2 + np);
        w3v[mi][0] = wv.x; w3v[mi][1] = wv.y; w3v[mi][2] = wv.z; w3v[mi][3] = wv.w;
        b2v[mi][0] = bv.x; b2v[mi][1] = bv.y; b2v[mi][2] = bv.z; b2v[mi][3] = bv.w;
    }
#pragma unroll
    for (int ni = 0; ni < 4; ++ni) {
        float s = 0.0f;
#pragma unroll
        for (int mi = 0; mi < 4; ++mi)
#pragma unroll
            for (int rg = 0; rg < 4; ++rg)
                s += elu1(acc2[mi][ni][rg] + b2v[mi][rg]) * w3v[mi][rg];
        s += __shfl_xor(s, 16);
        s += __shfl_xor(s, 32);
        if (lq == 0) part[wave][ni * 16 + ln] = s;
    }
    bar_lds();
    if (t < 64) {
        float s = b3[0];
#pragma unroll
        for (int w = 0; w < 4; ++w) s += part[w][t];
        fsi[(size_t)kidx * NB + b0 + t] = s;
    }
}

// ---------------- kernel 2: softmax over rules + consequent + weighted sum ----
// grid: 256 blocks x 512 threads; block = 32 batch rows.
// Wave (cg = wave&3, half = wave>>2) computes its 8 rules x 32 rows x 16
// classes: each Wc fragment load (bb0/bb1) now feeds MFMAs for BOTH 16-row
// sets -> Wc L2 traffic and per-rule loop overhead halved vs round 11
// (256MB -> 128MB grid-wide). Same kp/k0i/accumulation order per output row
// -> bit-identical results.
__global__ __launch_bounds__(512, 2) void cons_kernel(
    const float* __restrict__ x, const unsigned short* __restrict__ Wcb,
    const float* __restrict__ bc, const float* __restrict__ fsi,
    const int* __restrict__ ridx, float* __restrict__ outp,
    float* __restrict__ fire_out)
{
    __shared__ unsigned short xl[32 * 264];
    __shared__ float fire[32][NK];
    __shared__ float pred[4][32][16];   // half-1 partials

    const int t  = threadIdx.x;
    const int b0 = blockIdx.x * 32;

    int rr[NK];
#pragma unroll
    for (int k = 0; k < NK; ++k) rr[k] = ridx[k];

    // x -> bf16 LDS (32 rows x 256 cols, 512 threads x 4 float4)
#pragma unroll
    for (int i = 0; i < 4; ++i) {
        int idx = t + i * 512;
        int row = idx >> 6, col = (idx & 63) * 4;
        const float4 xv = *(const float4*)(x + (size_t)(b0 + row) * NF + col);
        uint2 pk;
        pk.x = pk2bf(xv.x, xv.y);
        pk.y = pk2bf(xv.z, xv.w);
        *(uint2*)(xl + row * 264 + col) = pk;
    }
    // softmax over 16 rules: thread = (row = t>>4, k = t&15), all 512 threads
    {
        const int row = t >> 4, k = t & 15;
        float v = fsi[(size_t)k * NB + b0 + row];
        float mx = v;
        mx = fmaxf(mx, __shfl_xor(mx, 1));
        mx = fmaxf(mx, __shfl_xor(mx, 2));
        mx = fmaxf(mx, __shfl_xor(mx, 4));
        mx = fmaxf(mx, __shfl_xor(mx, 8));
        float e = __expf(v - mx);
        float sum = e;
        sum += __shfl_xor(sum, 1);
        sum += __shfl_xor(sum, 2);
        sum += __shfl_xor(sum, 4);
        sum += __shfl_xor(sum, 8);
        float fv = e / sum;
        fire[row][k] = fv;
        fire_out[(size_t)b0 * NK + t] = fv;   // (b0+row)*16 + k == b0*16 + t
    }
    __syncthreads();

    const int wave = t >> 6, lane = t & 63;
    const int ln = lane & 15, lq = lane >> 4;
    const int cg = wave & 3, half = wave >> 2;
    const int nb = cg * 16;

    // A-fragments for BOTH 16-row sets, cached in registers
    short8 afr[2][8];
#pragma unroll
    for (int s = 0; s < 2; ++s)
#pragma unroll
        for (int k0i = 0; k0i < 8; ++k0i)
            afr[s][k0i] = *(const short8*)(xl + (s * 16 + ln) * 264 + k0i * 32 + lq * 8);

    floatx4 oacc0 = {0.0f, 0.0f, 0.0f, 0.0f};
    floatx4 oacc1 = {0.0f, 0.0f, 0.0f, 0.0f};
#pragma unroll
    for (int kp = 0; kp < 4; ++kp) {
        const int k0r = half * 8 + kp * 2;
        const int r0 = rr[k0r], r1 = rr[k0r + 1];
        // fragment-major: frag (r, cg, k0i) at ((r*4 + cg)*8 + k0i)*512 ushorts
        const unsigned short* Wr0 = Wcb + ((size_t)(r0 * 4 + cg) * 8) * 512 + lane * 8;
        const unsigned short* Wr1 = Wcb + ((size_t)(r1 * 4 + cg) * 8) * 512 + lane * 8;
        floatx4 a00 = {0.0f, 0.0f, 0.0f, 0.0f};   // rule0 x rowset0
        floatx4 a01 = {0.0f, 0.0f, 0.0f, 0.0f};   // rule0 x rowset1
        floatx4 a10 = {0.0f, 0.0f, 0.0f, 0.0f};   // rule1 x rowset0
        floatx4 a11 = {0.0f, 0.0f, 0.0f, 0.0f};   // rule1 x rowset1
#pragma unroll
        for (int k0i = 0; k0i < 8; ++k0i) {
            short8 bb0 = *(const short8*)(Wr0 + k0i * 512);
            short8 bb1 = *(const short8*)(Wr1 + k0i * 512);
            a00 = __builtin_amdgcn_mfma_f32_16x16x32_bf16(afr[0][k0i], bb0, a00, 0, 0, 0);
            a01 = __builtin_amdgcn_mfma_f32_16x16x32_bf16(afr[1][k0i], bb0, a01, 0, 0, 0);
            a10 = __builtin_amdgcn_mfma_f32_16x16x32_bf16(afr[0][k0i], bb1, a10, 0, 0, 0);
            a11 = __builtin_amdgcn_mfma_f32_16x16x32_bf16(afr[1][k0i], bb1, a11, 0, 0, 0);
        }
        const float bias0 = bc[(size_t)r0 * NC + nb + ln];
        const float bias1 = bc[(size_t)r1 * NC + nb + ln];
#pragma unroll
        for (int rg = 0; rg < 4; ++rg) {
            const int row0 = lq * 4 + rg;
            const int row1 = 16 + lq * 4 + rg;
            oacc0[rg] += fmaxf(a00[rg] + bias0, 0.0f) * fire[row0][k0r]
                       + fmaxf(a10[rg] + bias1, 0.0f) * fire[row0][k0r + 1];
            oacc1[rg] += fmaxf(a01[rg] + bias0, 0.0f) * fire[row1][k0r]
                       + fmaxf(a11[rg] + bias1, 0.0f) * fire[row1][k0r + 1];
        }
    }
    if (half == 1) {
#pragma unroll
        for (int rg = 0; rg < 4; ++rg) {
            pred[cg][lq * 4 + rg][ln]      = oacc0[rg];
            pred[cg][16 + lq * 4 + rg][ln] = oacc1[rg];
        }
    }
    __syncthreads();
    if (half == 0) {
#pragma unroll
        for (int rg = 0; rg < 4; ++rg) {
            outp[(size_t)(b0 + lq * 4 + rg) * NC + nb + ln] =
                oacc0[rg] + pred[cg][lq * 4 + rg][ln];
            outp[(size_t)(b0 + 16 + lq * 4 + rg) * NC + nb + ln] =
                oacc1[rg] + pred[cg][16 + lq * 4 + rg][ln];
        }
    }
}

extern "C" void kernel_launch(void* const* d_in, const int* in_sizes, int n_in,
                              void* d_out, int out_size, void* d_ws, size_t ws_size,
                              hipStream_t stream)
{
    (void)in_sizes; (void)n_in; (void)out_size;
    if (ws_size < 2097152) return;

    const float* x     = (const float*)d_in[0];
    const float* proto = (const float*)d_in[1];
    const float* var   = (const float*)d_in[2];
    const float* W1    = (const float*)d_in[3];
    const float* b1    = (const float*)d_in[4];
    const float* W2    = (const float*)d_in[5];
    const float* b2    = (const float*)d_in[6];
    const float* W3    = (const float*)d_in[7];
    const float* b3    = (const float*)d_in[8];
    const float* Wc    = (const float*)d_in[9];
    const float* bc    = (const float*)d_in[10];
    const int*   ridx  = (const int*)d_in[11];

    unsigned short* wb  = (unsigned short*)d_ws;
    unsigned short* W1b = wb;                 // 131072 (fragment-transposed)
    unsigned short* W2b = wb + 131072;        // 131072 (fragment-transposed)
    unsigned short* Wcb = wb + 262144;        // 524288 (fragment-transposed)
    float* fsi = (float*)((char*)d_ws + (size_t)786432 * 2);

    float* outp     = (float*)d_out;
    float* fire_out = outp + (size_t)NB * NC;

    conv_kernel<<<3072, 256, 0, stream>>>(W1, W2, Wc, wb);

    const int fs_lds = 2 * 64 * 256 * 2;  // 65536 B dynamic (+1KB static part[])
    hipFuncSetAttribute((const void*)fs_kernel,
                        hipFuncAttributeMaxDynamicSharedMemorySize, fs_lds);
    fs_kernel<<<2048, 256, fs_lds, stream>>>(x, proto, var, W1b, b1, W2b, b2,
                                             W3, b3, ridx, fsi);
    cons_kernel<<<256, 512, 0, stream>>>(x, Wcb, bc, fsi, ridx, outp, fire_out);
}

// Round 14
// 179.545 us; speedup vs baseline: 1.5673x; 1.0132x over previous
//
#include <hip/hip_runtime.h>
#include <hip/hip_bf16.h>
#include <cstdint>
#include <cstddef>

#define NF 256   // features
#define NG 512   // hidden (2F)
#define NC 64    // classes
#define NB 8192  // batch
#define NK 16    // active rules
#define BT 64    // fs batch tile

typedef __attribute__((ext_vector_type(8))) short short8;
typedef __attribute__((ext_vector_type(4))) float floatx4;

__device__ __forceinline__ unsigned short f2bf(float f) {
    union { float f; unsigned int u; } a; a.f = f;
    unsigned int u = a.u;
    u += 0x7fffu + ((u >> 16) & 1u);   // RNE
    return (unsigned short)(u >> 16);
}
__device__ __forceinline__ float elu1(float z) {
    return z > 0.0f ? z : (__expf(z) - 1.0f);
}
// HW-packed f32x2 -> bf16x2 (v_cvt_pk_bf16_f32, RNE — bit-identical to f2bf)
__device__ __forceinline__ unsigned int pk2bf(float a, float b) {
    __hip_bfloat162 h = __float22bfloat162_rn(make_float2(a, b));
    union { __hip_bfloat162 h; unsigned int u; } cv; cv.h = h; return cv.u;
}

// LDS-only barrier: orders ds ops across the workgroup WITHOUT draining vmcnt.
__device__ __forceinline__ void bar_lds() {
    __builtin_amdgcn_sched_barrier(0);
    asm volatile("s_waitcnt lgkmcnt(0)" ::: "memory");
    __builtin_amdgcn_s_barrier();
    __builtin_amdgcn_sched_barrier(0);
}

// ---------------- kernel 0: weights fp32 -> bf16, ALL FRAGMENT-TRANSPOSED ----
// (verbatim round 11 — verified)
__global__ __launch_bounds__(256) void conv_kernel(
    const float* __restrict__ W1, const float* __restrict__ W2,
    const float* __restrict__ Wc, unsigned short* __restrict__ wb)
{
    int i = blockIdx.x * 256 + threadIdx.x;
    if (i < 131072) {            // W1t: 32 N-blocks x 8 K-blocks
        int e = i & 7, l = (i >> 3) & 63, K = (i >> 9) & 7, N = i >> 12;
        int src = (N * 16 + (l & 15)) * NF + K * 32 + (l >> 4) * 8 + e;
        wb[i] = f2bf(W1[src]);
    } else if (i < 262144) {     // W2t: 16 N-blocks x 16 K-blocks
        int o = i - 131072;
        int e = o & 7, l = (o >> 3) & 63, K = (o >> 9) & 15, N = o >> 13;
        int src = (N * 16 + (l & 15)) * NG + K * 32 + (l >> 4) * 8 + e;
        wb[i] = f2bf(W2[src]);
    } else if (i < 786432) {     // Wct: 32 rules x 4 N-blocks x 8 K-blocks
        int o = i - 262144;
        int e = o & 7, l = (o >> 3) & 63, K = (o >> 9) & 7, N = (o >> 12) & 3, r = o >> 14;
        int src = (r * NC + N * 16 + (l & 15)) * NF + K * 32 + (l >> 4) * 8 + e;
        wb[i] = f2bf(Wc[src]);
    }
}

// ---------------- kernel 1: fused membership -> MLP -> fsi -------------------
// Round 10/11 structure with FULL UNROLL everywhere (P0, both GEMM k-loops,
// and the c-chunk loop). With fragment-contiguous weights every load address
// folds to base + immediate and the scheduler can hoist loads freely —
// attacks the remaining VALU bill (49% busy, the critical pipe). Code size
// ~16KB (I$ resident; R9 proved size is harmless). FP order identical.
__global__ __launch_bounds__(256, 2) void fs_kernel(
    const float* __restrict__ x, const float* __restrict__ proto,
    const float* __restrict__ var, const unsigned short* __restrict__ W1b,
    const float* __restrict__ b1, const unsigned short* __restrict__ W2b,
    const float* __restrict__ b2, const float* __restrict__ W3,
    const float* __restrict__ b3, const int* __restrict__ ridx,
    float* __restrict__ fsi)
{
    extern __shared__ unsigned short smem[];
    __shared__ float part[4][64];
    unsigned short* mv   = smem;              // [64][256] swizzled (512 B rows)
    unsigned short* cbuf = smem + 64 * 256;   // [64][256] swizzled, reused per chunk

    const int t   = threadIdx.x;
    const int pid = blockIdx.x;
    const int lg  = (pid & 7) * 256 + (pid >> 3);
    const int kidx = lg & 15;
    const int tile = lg >> 4;
    const int r    = ridx[kidx];
    const int b0   = tile * BT;

    const int wave = t >> 6, lane = t & 63;
    const int ln = lane & 15, lq = lane >> 4;
    const int sxr = (ln & 7) << 4;            // swizzle term (row&7 == ln&7)

    // ---- P0: membership mv = exp(-(x-p)^2/(2 v^2)), v=clip(var,1e-4,0.1) ----
    {
        const int col   = (t & 63) * 4;
        const int colb  = (t & 63) * 8;
        const int rbase = t >> 6;             // 0..3
        const float4 p4 = *(const float4*)(proto + (size_t)r * NF + col);
        float4 v4 = *(const float4*)(var + (size_t)r * NF + col);
        float cx = fminf(fmaxf(v4.x, 1e-4f), 0.1f);
        float cy = fminf(fmaxf(v4.y, 1e-4f), 0.1f);
        float cz = fminf(fmaxf(v4.z, 1e-4f), 0.1f);
        float cw = fminf(fmaxf(v4.w, 1e-4f), 0.1f);
        const float L2E = 1.44269504088896340736f;   // fold log2e: __expf(z)
        float ix = (0.5f * L2E) / (cx * cx);         // == exp2(z*log2e)
        float iy = (0.5f * L2E) / (cy * cy);
        float iz = (0.5f * L2E) / (cz * cz);
        float iw = (0.5f * L2E) / (cw * cw);
#pragma unroll
        for (int i = 0; i < 16; ++i) {
            int row = i * 4 + rbase;
            const float4 xv = *(const float4*)(x + (size_t)(b0 + row) * NF + col);
            float dx = xv.x - p4.x, dy = xv.y - p4.y, dz = xv.z - p4.z, dw = xv.w - p4.w;
            uint2 pk;
            pk.x = pk2bf(exp2f(-dx * dx * ix), exp2f(-dy * dy * iy));
            pk.y = pk2bf(exp2f(-dz * dz * iz), exp2f(-dw * dw * iw));
            *(uint2*)((char*)mv + row * 512 + (colb ^ ((row & 7) << 4))) = pk;
        }
    }
    bar_lds();

    floatx4 acc2[4][4];
#pragma unroll
    for (int mi = 0; mi < 4; ++mi)
#pragma unroll
        for (int ni = 0; ni < 4; ++ni) {
            floatx4 z = {0.0f, 0.0f, 0.0f, 0.0f};
            acc2[mi][ni] = z;
        }

#pragma unroll
    for (int c = 0; c < 2; ++c) {
        floatx4 acc1[4][4];
#pragma unroll
        for (int mi = 0; mi < 4; ++mi)
#pragma unroll
            for (int ni = 0; ni < 4; ++ni) {
                floatx4 z = {0.0f, 0.0f, 0.0f, 0.0f};
                acc1[mi][ni] = z;
            }
        const unsigned short* w1p = W1b + c * 65536 + wave * 16384 + lane * 8;
#pragma unroll
        for (int k0i = 0; k0i < 8; ++k0i) {
            short8 a[4], b[4];
#pragma unroll
            for (int mi = 0; mi < 4; ++mi)
                a[mi] = *(const short8*)(w1p + mi * 4096 + k0i * 512);
#pragma unroll
            for (int ni = 0; ni < 4; ++ni)
                b[ni] = *(const short8*)((const char*)mv + (ni * 16 + ln) * 512
                                         + ((k0i * 64 + lq * 16) ^ sxr));
#pragma unroll
            for (int ni = 0; ni < 4; ++ni)
#pragma unroll
                for (int mi = 0; mi < 4; ++mi)
                    acc1[mi][ni] = __builtin_amdgcn_mfma_f32_16x16x32_bf16(
                        a[mi], b[ni], acc1[mi][ni], 0, 0, 0);
        }
        bar_lds();
#pragma unroll
        for (int mi = 0; mi < 4; ++mi) {
            const int nl = wave * 64 + mi * 16 + lq * 4;
            const float4 b4 = *(const float4*)(b1 + c * 256 + nl);
#pragma unroll
            for (int ni = 0; ni < 4; ++ni) {
                uint2 pk;
                pk.x = pk2bf(elu1(acc1[mi][ni][0] + b4.x),
                             elu1(acc1[mi][ni][1] + b4.y));
                pk.y = pk2bf(elu1(acc1[mi][ni][2] + b4.z),
                             elu1(acc1[mi][ni][3] + b4.w));
                *(uint2*)((char*)cbuf + (ni * 16 + ln) * 512 + ((nl * 2) ^ sxr)) = pk;
            }
        }
        bar_lds();
        const unsigned short* w2p = W2b + wave * 32768 + c * 8 * 512 + lane * 8;
#pragma unroll
        for (int k0i = 0; k0i < 8; ++k0i) {
            short8 a[4], b[4];
#pragma unroll
            for (int mi = 0; mi < 4; ++mi)
                a[mi] = *(const short8*)(w2p + mi * 8192 + k0i * 512);
#pragma unroll
            for (int ni = 0; ni < 4; ++ni)
                b[ni] = *(const short8*)((const char*)cbuf + (ni * 16 + ln) * 512
                                         + ((k0i * 64 + lq * 16) ^ sxr));
#pragma unroll
            for (int ni = 0; ni < 4; ++ni)
#pragma unroll
                for (int mi = 0; mi < 4; ++mi)
                    acc2[mi][ni] = __builtin_amdgcn_mfma_f32_16x16x32_bf16(
                        a[mi], b[ni], acc2[mi][ni], 0, 0, 0);
        }
    }

    float w3v[4][4], b2v[4][4];
#pragma unroll
    for (int mi = 0; mi < 4; ++mi) {
        const int np = wave * 64 + mi * 16 + lq * 4;
        const float4 wv = *(const float4*)(W3 + np);
        const float4 bv = *(const float4*)(b2 + np);
        w3v[mi][0] = wv.x; w3v[mi][1] = wv.y; w3v[mi][2] = wv.z; w3v[mi][3] = wv.w;
        b2v[mi][0] = bv.x; b2v[mi][1] = bv.y; b2v[mi][2] = bv.z; b2v[mi][3] = bv.w;
    }
#pragma unroll
    for (int ni = 0; ni < 4; ++ni) {
        float s = 0.0f;
#pragma unroll
        for (int mi = 0; mi < 4; ++mi)
#pragma unroll
            for (int rg = 0; rg < 4; ++rg)
                s += elu1(acc2[mi][ni][rg] + b2v[mi][rg]) * w3v[mi][rg];
        s += __shfl_xor(s, 16);
        s += __shfl_xor(s, 32);
        if (lq == 0) part[wave][ni * 16 + ln] = s;
    }
    bar_lds();
    if (t < 64) {
        float s = b3[0];
#pragma unroll
        for (int w = 0; w < 4; ++w) s += part[w][t];
        fsi[(size_t)kidx * NB + b0 + t] = s;
    }
}

// ---------------- kernel 2: softmax over rules + consequent + weighted sum ----
// (verbatim round 11 — verified best: 512 blocks x 512 threads, 16 rows,
// halves split over rules, fragment-contiguous Wc loads)
__global__ __launch_bounds__(512, 4) void cons_kernel(
    const float* __restrict__ x, const unsigned short* __restrict__ Wcb,
    const float* __restrict__ bc, const float* __restrict__ fsi,
    const int* __restrict__ ridx, float* __restrict__ outp,
    float* __restrict__ fire_out)
{
    __shared__ unsigned short xl[16 * 264];
    __shared__ float fire[16][NK];
    __shared__ float pred[4][16][16];

    const int t  = threadIdx.x;
    const int b0 = blockIdx.x * 16;

    int rr[NK];
#pragma unroll
    for (int k = 0; k < NK; ++k) rr[k] = ridx[k];

    {
        int idx = t;
#pragma unroll
        for (int i = 0; i < 2; ++i, idx += 512) {
            int row = idx >> 6, col = (idx & 63) * 4;
            const float4 xv = *(const float4*)(x + (size_t)(b0 + row) * NF + col);
            uint2 pk;
            pk.x = pk2bf(xv.x, xv.y);
            pk.y = pk2bf(xv.z, xv.w);
            *(uint2*)(xl + row * 264 + col) = pk;
        }
    }
    if (t < 256) {
        const int row = t >> 4, k = t & 15;
        float v = fsi[(size_t)k * NB + b0 + row];
        float mx = v;
        mx = fmaxf(mx, __shfl_xor(mx, 1));
        mx = fmaxf(mx, __shfl_xor(mx, 2));
        mx = fmaxf(mx, __shfl_xor(mx, 4));
        mx = fmaxf(mx, __shfl_xor(mx, 8));
        float e = __expf(v - mx);
        float sum = e;
        sum += __shfl_xor(sum, 1);
        sum += __shfl_xor(sum, 2);
        sum += __shfl_xor(sum, 4);
        sum += __shfl_xor(sum, 8);
        float fv = e / sum;
        fire[row][k] = fv;
        fire_out[(size_t)b0 * NK + t] = fv;
    }
    __syncthreads();

    const int wave = t >> 6, lane = t & 63;
    const int ln = lane & 15, lq = lane >> 4;
    const int cg = wave & 3, half = wave >> 2;
    const int nb = cg * 16;

    short8 afr[8];
#pragma unroll
    for (int k0i = 0; k0i < 8; ++k0i)
        afr[k0i] = *(const short8*)(xl + ln * 264 + k0i * 32 + lq * 8);

    floatx4 oacc = {0.0f, 0.0f, 0.0f, 0.0f};
#pragma unroll
    for (int kp = 0; kp < 4; ++kp) {
        const int k0r = half * 8 + kp * 2;
        const int r0 = rr[k0r], r1 = rr[k0r + 1];
        const unsigned short* Wr0 = Wcb + ((size_t)(r0 * 4 + cg) * 8) * 512 + lane * 8;
        const unsigned short* Wr1 = Wcb + ((size_t)(r1 * 4 + cg) * 8) * 512 + lane * 8;
        floatx4 a0 = {0.0f, 0.0f, 0.0f, 0.0f};
        floatx4 a1 = {0.0f, 0.0f, 0.0f, 0.0f};
#pragma unroll
        for (int k0i = 0; k0i < 8; ++k0i) {
            short8 bb0 = *(const short8*)(Wr0 + k0i * 512);
            short8 bb1 = *(const short8*)(Wr1 + k0i * 512);
            a0 = __builtin_amdgcn_mfma_f32_16x16x32_bf16(afr[k0i], bb0, a0, 0, 0, 0);
            a1 = __builtin_amdgcn_mfma_f32_16x16x32_bf16(afr[k0i], bb1, a1, 0, 0, 0);
        }
        const float bias0 = bc[(size_t)r0 * NC + nb + ln];
        const float bias1 = bc[(size_t)r1 * NC + nb + ln];
#pragma unroll
        for (int rg = 0; rg < 4; ++rg) {
            const int row = lq * 4 + rg;
            oacc[rg] += fmaxf(a0[rg] + bias0, 0.0f) * fire[row][k0r]
                      + fmaxf(a1[rg] + bias1, 0.0f) * fire[row][k0r + 1];
        }
    }
    if (half == 1) {
#pragma unroll
        for (int rg = 0; rg < 4; ++rg)
            pred[cg][lq * 4 + rg][ln] = oacc[rg];
    }
    __syncthreads();
    if (half == 0) {
#pragma unroll
        for (int rg = 0; rg < 4; ++rg)
            outp[(size_t)(b0 + lq * 4 + rg) * NC + nb + ln] =
                oacc[rg] + pred[cg][lq * 4 + rg][ln];
    }
}

extern "C" void kernel_launch(void* const* d_in, const int* in_sizes, int n_in,
                              void* d_out, int out_size, void* d_ws, size_t ws_size,
                              hipStream_t stream)
{
    (void)in_sizes; (void)n_in; (void)out_size;
    if (ws_size < 2097152) return;

    const float* x     = (const float*)d_in[0];
    const float* proto = (const float*)d_in[1];
    const float* var   = (const float*)d_in[2];
    const float* W1    = (const float*)d_in[3];
    const float* b1    = (const float*)d_in[4];
    const float* W2    = (const float*)d_in[5];
    const float* b2    = (const float*)d_in[6];
    const float* W3    = (const float*)d_in[7];
    const float* b3    = (const float*)d_in[8];
    const float* Wc    = (const float*)d_in[9];
    const float* bc    = (const float*)d_in[10];
    const int*   ridx  = (const int*)d_in[11];

    unsigned short* wb  = (unsigned short*)d_ws;
    unsigned short* W1b = wb;                 // 131072 (fragment-transposed)
    unsigned short* W2b = wb + 131072;        // 131072 (fragment-transposed)
    unsigned short* Wcb = wb + 262144;        // 524288 (fragment-transposed)
    float* fsi = (float*)((char*)d_ws + (size_t)786432 * 2);

    float* outp     = (float*)d_out;
    float* fire_out = outp + (size_t)NB * NC;

    conv_kernel<<<3072, 256, 0, stream>>>(W1, W2, Wc, wb);

    const int fs_lds = 2 * 64 * 256 * 2;  // 65536 B dynamic (+1KB static part[])
    hipFuncSetAttribute((const void*)fs_kernel,
                        hipFuncAttributeMaxDynamicSharedMemorySize, fs_lds);
    fs_kernel<<<2048, 256, fs_lds, stream>>>(x, proto, var, W1b, b1, W2b, b2,
                                             W3, b3, ridx, fsi);
    cons_kernel<<<512, 512, 0, stream>>>(x, Wcb, bc, fsi, ridx, outp, fire_out);
}

// Round 15
// 178.063 us; speedup vs baseline: 1.5804x; 1.0083x over previous
//
#include <hip/hip_runtime.h>
#include <hip/hip_bf16.h>
#include <cstdint>
#include <cstddef>

#define NF 256   // features
#define NG 512   // hidden (2F)
#define NC 64    // classes
#define NB 8192  // batch
#define NK 16    // active rules
#define BT 64    // fs batch tile

typedef __attribute__((ext_vector_type(8))) short short8;
typedef __attribute__((ext_vector_type(4))) float floatx4;

__device__ __forceinline__ unsigned short f2bf(float f) {
    union { float f; unsigned int u; } a; a.f = f;
    unsigned int u = a.u;
    u += 0x7fffu + ((u >> 16) & 1u);   // RNE
    return (unsigned short)(u >> 16);
}
__device__ __forceinline__ float elu1(float z) {
    return z > 0.0f ? z : (__expf(z) - 1.0f);
}
// HW-packed f32x2 -> bf16x2 (v_cvt_pk_bf16_f32, RNE — bit-identical to f2bf)
__device__ __forceinline__ unsigned int pk2bf(float a, float b) {
    __hip_bfloat162 h = __float22bfloat162_rn(make_float2(a, b));
    union { __hip_bfloat162 h; unsigned int u; } cv; cv.h = h; return cv.u;
}

// LDS-only barrier: orders ds ops across the workgroup WITHOUT draining vmcnt.
__device__ __forceinline__ void bar_lds() {
    __builtin_amdgcn_sched_barrier(0);
    asm volatile("s_waitcnt lgkmcnt(0)" ::: "memory");
    __builtin_amdgcn_s_barrier();
    __builtin_amdgcn_sched_barrier(0);
}

// ---------------- kernel 0: weights fp32 -> bf16, ALL FRAGMENT-TRANSPOSED ----
// W1t/W2t/Wct in MFMA-fragment order: fragment (N-block, K-block) is a
// contiguous 1024 B run. fs/cons weight loads become base + immediate:
// zero per-step address VALU, one contiguous 1KB request per instruction
// (the fix that took fs 155->95us and cons's share down 16us).
__global__ __launch_bounds__(256) void conv_kernel(
    const float* __restrict__ W1, const float* __restrict__ W2,
    const float* __restrict__ Wc, unsigned short* __restrict__ wb)
{
    int i = blockIdx.x * 256 + threadIdx.x;
    if (i < 131072) {            // W1t: 32 N-blocks x 8 K-blocks
        int e = i & 7, l = (i >> 3) & 63, K = (i >> 9) & 7, N = i >> 12;
        int src = (N * 16 + (l & 15)) * NF + K * 32 + (l >> 4) * 8 + e;
        wb[i] = f2bf(W1[src]);
    } else if (i < 262144) {     // W2t: 16 N-blocks x 16 K-blocks
        int o = i - 131072;
        int e = o & 7, l = (o >> 3) & 63, K = (o >> 9) & 15, N = o >> 13;
        int src = (N * 16 + (l & 15)) * NG + K * 32 + (l >> 4) * 8 + e;
        wb[i] = f2bf(W2[src]);
    } else if (i < 786432) {     // Wct: 32 rules x 4 N-blocks x 8 K-blocks
        int o = i - 262144;
        int e = o & 7, l = (o >> 3) & 63, K = (o >> 9) & 7, N = (o >> 12) & 3, r = o >> 14;
        int src = (r * NC + N * 16 + (l & 15)) * NF + K * 32 + (l >> 4) * 8 + e;
        wb[i] = f2bf(Wc[src]);
    }
}

// ---------------- kernel 1: fused membership -> MLP -> fsi -------------------
// Round 10/11 verbatim (verified 95-97us): rolled loops at the proven unroll-2
// cadence (R14 proved full unroll regresses), swizzled LDS, XCD swizzle,
// bar_lds, fragment-contiguous weight loads, pk2bf packing, exp2 fold.
__global__ __launch_bounds__(256, 2) void fs_kernel(
    const float* __restrict__ x, const float* __restrict__ proto,
    const float* __restrict__ var, const unsigned short* __restrict__ W1b,
    const float* __restrict__ b1, const unsigned short* __restrict__ W2b,
    const float* __restrict__ b2, const float* __restrict__ W3,
    const float* __restrict__ b3, const int* __restrict__ ridx,
    float* __restrict__ fsi)
{
    extern __shared__ unsigned short smem[];
    __shared__ float part[4][64];
    unsigned short* mv   = smem;              // [64][256] swizzled (512 B rows)
    unsigned short* cbuf = smem + 64 * 256;   // [64][256] swizzled, reused per chunk

    const int t   = threadIdx.x;
    const int pid = blockIdx.x;
    const int lg  = (pid & 7) * 256 + (pid >> 3);
    const int kidx = lg & 15;
    const int tile = lg >> 4;
    const int r    = ridx[kidx];
    const int b0   = tile * BT;

    const int wave = t >> 6, lane = t & 63;
    const int ln = lane & 15, lq = lane >> 4;
    const int sxr = (ln & 7) << 4;            // swizzle term (row&7 == ln&7)

    // ---- P0: membership mv = exp(-(x-p)^2/(2 v^2)), v=clip(var,1e-4,0.1) ----
    {
        const int col   = (t & 63) * 4;
        const int colb  = (t & 63) * 8;
        const int rbase = t >> 6;             // 0..3
        const float4 p4 = *(const float4*)(proto + (size_t)r * NF + col);
        float4 v4 = *(const float4*)(var + (size_t)r * NF + col);
        float cx = fminf(fmaxf(v4.x, 1e-4f), 0.1f);
        float cy = fminf(fmaxf(v4.y, 1e-4f), 0.1f);
        float cz = fminf(fmaxf(v4.z, 1e-4f), 0.1f);
        float cw = fminf(fmaxf(v4.w, 1e-4f), 0.1f);
        const float L2E = 1.44269504088896340736f;   // fold log2e: __expf(z)
        float ix = (0.5f * L2E) / (cx * cx);         // == exp2(z*log2e)
        float iy = (0.5f * L2E) / (cy * cy);
        float iz = (0.5f * L2E) / (cz * cz);
        float iw = (0.5f * L2E) / (cw * cw);
#pragma unroll 4
        for (int i = 0; i < 16; ++i) {
            int row = i * 4 + rbase;
            const float4 xv = *(const float4*)(x + (size_t)(b0 + row) * NF + col);
            float dx = xv.x - p4.x, dy = xv.y - p4.y, dz = xv.z - p4.z, dw = xv.w - p4.w;
            uint2 pk;
            pk.x = pk2bf(exp2f(-dx * dx * ix), exp2f(-dy * dy * iy));
            pk.y = pk2bf(exp2f(-dz * dz * iz), exp2f(-dw * dw * iw));
            *(uint2*)((char*)mv + row * 512 + (colb ^ ((row & 7) << 4))) = pk;
        }
    }
    bar_lds();

    floatx4 acc2[4][4];
#pragma unroll
    for (int mi = 0; mi < 4; ++mi)
#pragma unroll
        for (int ni = 0; ni < 4; ++ni) {
            floatx4 z = {0.0f, 0.0f, 0.0f, 0.0f};
            acc2[mi][ni] = z;
        }

#pragma unroll 1
    for (int c = 0; c < 2; ++c) {
        floatx4 acc1[4][4];
#pragma unroll
        for (int mi = 0; mi < 4; ++mi)
#pragma unroll
            for (int ni = 0; ni < 4; ++ni) {
                floatx4 z = {0.0f, 0.0f, 0.0f, 0.0f};
                acc1[mi][ni] = z;
            }
        const unsigned short* w1p = W1b + c * 65536 + wave * 16384 + lane * 8;
#pragma unroll 2
        for (int k0i = 0; k0i < 8; ++k0i) {
            short8 a[4], b[4];
#pragma unroll
            for (int mi = 0; mi < 4; ++mi)
                a[mi] = *(const short8*)(w1p + mi * 4096 + k0i * 512);
#pragma unroll
            for (int ni = 0; ni < 4; ++ni)
                b[ni] = *(const short8*)((const char*)mv + (ni * 16 + ln) * 512
                                         + ((k0i * 64 + lq * 16) ^ sxr));
#pragma unroll
            for (int ni = 0; ni < 4; ++ni)
#pragma unroll
                for (int mi = 0; mi < 4; ++mi)
                    acc1[mi][ni] = __builtin_amdgcn_mfma_f32_16x16x32_bf16(
                        a[mi], b[ni], acc1[mi][ni], 0, 0, 0);
        }
        bar_lds();
#pragma unroll
        for (int mi = 0; mi < 4; ++mi) {
            const int nl = wave * 64 + mi * 16 + lq * 4;
            const float4 b4 = *(const float4*)(b1 + c * 256 + nl);
#pragma unroll
            for (int ni = 0; ni < 4; ++ni) {
                uint2 pk;
                pk.x = pk2bf(elu1(acc1[mi][ni][0] + b4.x),
                             elu1(acc1[mi][ni][1] + b4.y));
                pk.y = pk2bf(elu1(acc1[mi][ni][2] + b4.z),
                             elu1(acc1[mi][ni][3] + b4.w));
                *(uint2*)((char*)cbuf + (ni * 16 + ln) * 512 + ((nl * 2) ^ sxr)) = pk;
            }
        }
        bar_lds();
        const unsigned short* w2p = W2b + wave * 32768 + c * 8 * 512 + lane * 8;
#pragma unroll 2
        for (int k0i = 0; k0i < 8; ++k0i) {
            short8 a[4], b[4];
#pragma unroll
            for (int mi = 0; mi < 4; ++mi)
                a[mi] = *(const short8*)(w2p + mi * 8192 + k0i * 512);
#pragma unroll
            for (int ni = 0; ni < 4; ++ni)
                b[ni] = *(const short8*)((const char*)cbuf + (ni * 16 + ln) * 512
                                         + ((k0i * 64 + lq * 16) ^ sxr));
#pragma unroll
            for (int ni = 0; ni < 4; ++ni)
#pragma unroll
                for (int mi = 0; mi < 4; ++mi)
                    acc2[mi][ni] = __builtin_amdgcn_mfma_f32_16x16x32_bf16(
                        a[mi], b[ni], acc2[mi][ni], 0, 0, 0);
        }
    }

    float w3v[4][4], b2v[4][4];
#pragma unroll
    for (int mi = 0; mi < 4; ++mi) {
        const int np = wave * 64 + mi * 16 + lq * 4;
        const float4 wv = *(const float4*)(W3 + np);
        const float4 bv = *(const float4*)(b2 + np);
        w3v[mi][0] = wv.x; w3v[mi][1] = wv.y; w3v[mi][2] = wv.z; w3v[mi][3] = wv.w;
        b2v[mi][0] = bv.x; b2v[mi][1] = bv.y; b2v[mi][2] = bv.z; b2v[mi][3] = bv.w;
    }
#pragma unroll
    for (int ni = 0; ni < 4; ++ni) {
        float s = 0.0f;
#pragma unroll
        for (int mi = 0; mi < 4; ++mi)
#pragma unroll
            for (int rg = 0; rg < 4; ++rg)
                s += elu1(acc2[mi][ni][rg] + b2v[mi][rg]) * w3v[mi][rg];
        s += __shfl_xor(s, 16);
        s += __shfl_xor(s, 32);
        if (lq == 0) part[wave][ni * 16 + ln] = s;
    }
    bar_lds();
    if (t < 64) {
        float s = b3[0];
#pragma unroll
        for (int w = 0; w < 4; ++w) s += part[w][t];
        fsi[(size_t)kidx * NB + b0 + t] = s;
    }
}

// ---------------- kernel 2: softmax over rules + consequent + weighted sum ----
// (verbatim round 11 — verified best: 512 blocks x 512 threads, 16 rows,
// halves split over rules, fragment-contiguous Wc loads)
__global__ __launch_bounds__(512, 4) void cons_kernel(
    const float* __restrict__ x, const unsigned short* __restrict__ Wcb,
    const float* __restrict__ bc, const float* __restrict__ fsi,
    const int* __restrict__ ridx, float* __restrict__ outp,
    float* __restrict__ fire_out)
{
    __shared__ unsigned short xl[16 * 264];
    __shared__ float fire[16][NK];
    __shared__ float pred[4][16][16];

    const int t  = threadIdx.x;
    const int b0 = blockIdx.x * 16;

    int rr[NK];
#pragma unroll
    for (int k = 0; k < NK; ++k) rr[k] = ridx[k];

    {
        int idx = t;
#pragma unroll
        for (int i = 0; i < 2; ++i, idx += 512) {
            int row = idx >> 6, col = (idx & 63) * 4;
            const float4 xv = *(const float4*)(x + (size_t)(b0 + row) * NF + col);
            uint2 pk;
            pk.x = pk2bf(xv.x, xv.y);
            pk.y = pk2bf(xv.z, xv.w);
            *(uint2*)(xl + row * 264 + col) = pk;
        }
    }
    if (t < 256) {
        const int row = t >> 4, k = t & 15;
        float v = fsi[(size_t)k * NB + b0 + row];
        float mx = v;
        mx = fmaxf(mx, __shfl_xor(mx, 1));
        mx = fmaxf(mx, __shfl_xor(mx, 2));
        mx = fmaxf(mx, __shfl_xor(mx, 4));
        mx = fmaxf(mx, __shfl_xor(mx, 8));
        float e = __expf(v - mx);
        float sum = e;
        sum += __shfl_xor(sum, 1);
        sum += __shfl_xor(sum, 2);
        sum += __shfl_xor(sum, 4);
        sum += __shfl_xor(sum, 8);
        float fv = e / sum;
        fire[row][k] = fv;
        fire_out[(size_t)b0 * NK + t] = fv;
    }
    __syncthreads();

    const int wave = t >> 6, lane = t & 63;
    const int ln = lane & 15, lq = lane >> 4;
    const int cg = wave & 3, half = wave >> 2;
    const int nb = cg * 16;

    short8 afr[8];
#pragma unroll
    for (int k0i = 0; k0i < 8; ++k0i)
        afr[k0i] = *(const short8*)(xl + ln * 264 + k0i * 32 + lq * 8);

    floatx4 oacc = {0.0f, 0.0f, 0.0f, 0.0f};
#pragma unroll
    for (int kp = 0; kp < 4; ++kp) {
        const int k0r = half * 8 + kp * 2;
        const int r0 = rr[k0r], r1 = rr[k0r + 1];
        const unsigned short* Wr0 = Wcb + ((size_t)(r0 * 4 + cg) * 8) * 512 + lane * 8;
        const unsigned short* Wr1 = Wcb + ((size_t)(r1 * 4 + cg) * 8) * 512 + lane * 8;
        floatx4 a0 = {0.0f, 0.0f, 0.0f, 0.0f};
        floatx4 a1 = {0.0f, 0.0f, 0.0f, 0.0f};
#pragma unroll
        for (int k0i = 0; k0i < 8; ++k0i) {
            short8 bb0 = *(const short8*)(Wr0 + k0i * 512);
            short8 bb1 = *(const short8*)(Wr1 + k0i * 512);
            a0 = __builtin_amdgcn_mfma_f32_16x16x32_bf16(afr[k0i], bb0, a0, 0, 0, 0);
            a1 = __builtin_amdgcn_mfma_f32_16x16x32_bf16(afr[k0i], bb1, a1, 0, 0, 0);
        }
        const float bias0 = bc[(size_t)r0 * NC + nb + ln];
        const float bias1 = bc[(size_t)r1 * NC + nb + ln];
#pragma unroll
        for (int rg = 0; rg < 4; ++rg) {
            const int row = lq * 4 + rg;
            oacc[rg] += fmaxf(a0[rg] + bias0, 0.0f) * fire[row][k0r]
                      + fmaxf(a1[rg] + bias1, 0.0f) * fire[row][k0r + 1];
        }
    }
    if (half == 1) {
#pragma unroll
        for (int rg = 0; rg < 4; ++rg)
            pred[cg][lq * 4 + rg][ln] = oacc[rg];
    }
    __syncthreads();
    if (half == 0) {
#pragma unroll
        for (int rg = 0; rg < 4; ++rg)
            outp[(size_t)(b0 + lq * 4 + rg) * NC + nb + ln] =
                oacc[rg] + pred[cg][lq * 4 + rg][ln];
    }
}

extern "C" void kernel_launch(void* const* d_in, const int* in_sizes, int n_in,
                              void* d_out, int out_size, void* d_ws, size_t ws_size,
                              hipStream_t stream)
{
    (void)in_sizes; (void)n_in; (void)out_size;
    if (ws_size < 2097152) return;

    const float* x     = (const float*)d_in[0];
    const float* proto = (const float*)d_in[1];
    const float* var   = (const float*)d_in[2];
    const float* W1    = (const float*)d_in[3];
    const float* b1    = (const float*)d_in[4];
    const float* W2    = (const float*)d_in[5];
    const float* b2    = (const float*)d_in[6];
    const float* W3    = (const float*)d_in[7];
    const float* b3    = (const float*)d_in[8];
    const float* Wc    = (const float*)d_in[9];
    const float* bc    = (const float*)d_in[10];
    const int*   ridx  = (const int*)d_in[11];

    unsigned short* wb  = (unsigned short*)d_ws;
    unsigned short* W1b = wb;                 // 131072 (fragment-transposed)
    unsigned short* W2b = wb + 131072;        // 131072 (fragment-transposed)
    unsigned short* Wcb = wb + 262144;        // 524288 (fragment-transposed)
    float* fsi = (float*)((char*)d_ws + (size_t)786432 * 2);

    float* outp     = (float*)d_out;
    float* fire_out = outp + (size_t)NB * NC;

    conv_kernel<<<3072, 256, 0, stream>>>(W1, W2, Wc, wb);

    const int fs_lds = 2 * 64 * 256 * 2;  // 65536 B dynamic (+1KB static part[])
    hipFuncSetAttribute((const void*)fs_kernel,
                        hipFuncAttributeMaxDynamicSharedMemorySize, fs_lds);
    fs_kernel<<<2048, 256, fs_lds, stream>>>(x, proto, var, W1b, b1, W2b, b2,
                                             W3, b3, ridx, fsi);
    cons_kernel<<<512, 512, 0, stream>>>(x, Wcb, bc, fsi, ridx, outp, fire_out);
}